// Round 1
// baseline (581.321 us; speedup 1.0000x reference)
//
#include <hip/hip_runtime.h>
#include <hip/hip_bf16.h>
#include <stdint.h>

typedef __hip_bfloat16 bf16;
typedef __attribute__((ext_vector_type(4))) float f32x4;
typedef __attribute__((ext_vector_type(8))) short bf16x8;

#define B_  2
#define S_  2048
#define HID_ 2048
#define NH_ 16
#define NKV_ 2
#define HD_ 128
#define QKV_N 2560           // (NH + 2*NKV) * HD
#define SCALE_ 0.08838834764831845f

// ---------------------------------------------------------------------------
// async 16B global->LDS (wave-uniform LDS base + lane*16)
__device__ __forceinline__ void async_load16(const void* g, void* l) {
    __builtin_amdgcn_global_load_lds(
        (const __attribute__((address_space(1))) unsigned int*)(uintptr_t)g,
        (__attribute__((address_space(3))) unsigned int*)(uintptr_t)l,
        16, 0, 0);
}

// ---------------------------------------------------------------------------
// cast fp32 -> bf16, 4 elems/thread, exact grid
__global__ void cast_f32_bf16(const float* __restrict__ in, bf16* __restrict__ out) {
    long idx = ((long)blockIdx.x * 256 + threadIdx.x) * 4;
    float4 v = *(const float4*)(in + idx);
    bf16 o[4];
    o[0] = __float2bfloat16(v.x); o[1] = __float2bfloat16(v.y);
    o[2] = __float2bfloat16(v.z); o[3] = __float2bfloat16(v.w);
    *(ulong1*)(out + idx) = *(ulong1*)o;
}

// transpose + cast: in fp32 [R][C] -> out bf16 [C][R]
__global__ void transpose_cast(const float* __restrict__ in, bf16* __restrict__ out,
                               int R, int C) {
    __shared__ float t[32][33];
    int tx = threadIdx.x & 31, ty = threadIdx.x >> 5;   // 32x8
    int c = blockIdx.x * 32 + tx;
#pragma unroll
    for (int j = 0; j < 4; j++) {
        int r = blockIdx.y * 32 + ty + j * 8;
        t[ty + j * 8][tx] = in[(long)r * C + c];
    }
    __syncthreads();
#pragma unroll
    for (int j = 0; j < 4; j++) {
        int cc = blockIdx.x * 32 + ty + j * 8;
        int rr = blockIdx.y * 32 + tx;
        out[(long)cc * R + rr] = __float2bfloat16(t[tx][ty + j * 8]);
    }
}

// ---------------------------------------------------------------------------
// m97-style GEMM: C[M,N] = A[M,K] * Bt[N,K]^T (+bias), 128x128 tile, BK=32
template <bool HAS_BIAS, bool OUT_BF16>
__global__ __launch_bounds__(256) void gemm128(
    const bf16* __restrict__ A, const bf16* __restrict__ Bt,
    const float* __restrict__ bias, void* __restrict__ Cout,
    int M, int N, int K)
{
    __shared__ __align__(16) bf16 As[128 * 32];
    __shared__ __align__(16) bf16 Bs[128 * 32];
    const int tid = threadIdx.x;
    const int wave = tid >> 6, lane = tid & 63;
    const int quad = lane >> 4, l16 = lane & 15;
    const int wr = wave >> 1, wc = wave & 1;
    const long row0 = (long)blockIdx.y * 128;
    const long col0 = (long)blockIdx.x * 128;

    f32x4 acc[4][4];
#pragma unroll
    for (int i = 0; i < 4; i++)
#pragma unroll
        for (int j = 0; j < 4; j++) acc[i][j] = {0.f, 0.f, 0.f, 0.f};

    for (int k0 = 0; k0 < K; k0 += 32) {
        __syncthreads();
#pragma unroll
        for (int i = 0; i < 2; i++) {
            int cb = i * 256 + wave * 64;           // wave-uniform chunk base
            int c = cb + lane;
            int r = c >> 2, kc = c & 3;
            async_load16(A + (row0 + r) * K + k0 + kc * 8, As + (size_t)cb * 8);
            async_load16(Bt + (col0 + r) * K + k0 + kc * 8, Bs + (size_t)cb * 8);
        }
        __syncthreads();   // drains vmcnt before ds_read

        bf16x8 af[4], bfr[4];
#pragma unroll
        for (int mi = 0; mi < 4; mi++)
            af[mi] = *(const bf16x8*)(As + (wr * 64 + mi * 16 + l16) * 32 + quad * 8);
#pragma unroll
        for (int ni = 0; ni < 4; ni++)
            bfr[ni] = *(const bf16x8*)(Bs + (wc * 64 + ni * 16 + l16) * 32 + quad * 8);
#pragma unroll
        for (int mi = 0; mi < 4; mi++)
#pragma unroll
            for (int ni = 0; ni < 4; ni++)
                acc[mi][ni] = __builtin_amdgcn_mfma_f32_16x16x32_bf16(
                    af[mi], bfr[ni], acc[mi][ni], 0, 0, 0);
    }

#pragma unroll
    for (int mi = 0; mi < 4; mi++) {
        long r = row0 + wr * 64 + mi * 16 + quad * 4;
#pragma unroll
        for (int ni = 0; ni < 4; ni++) {
            long c = col0 + wc * 64 + ni * 16 + l16;
            float bv = HAS_BIAS ? bias[c] : 0.0f;
#pragma unroll
            for (int reg = 0; reg < 4; reg++) {
                float v = acc[mi][ni][reg] + bv;
                if (OUT_BF16)
                    ((bf16*)Cout)[(r + reg) * N + c] = __float2bfloat16(v);
                else
                    ((float*)Cout)[(r + reg) * N + c] = v;
            }
        }
    }
}

// ---------------------------------------------------------------------------
// RoPE + split qkv[4096][2560] -> Q [B,NH,S,HD], K [B,NKV,S,HD], V [B,NKV,S,HD]
__global__ void rope_split(const bf16* __restrict__ qkv, const int* __restrict__ pos,
                           bf16* __restrict__ Qr, bf16* __restrict__ Kr,
                           bf16* __restrict__ Vr)
{
    int idx = blockIdx.x * 256 + threadIdx.x;    // B*S*20*64 total
    int r = idx / 1280;                          // b*S + s
    int rem = idx - r * 1280;
    int unit = rem >> 6;                         // 0..19
    int i = rem & 63;
    int b = r >> 11;                             // S=2048
    int s = r & 2047;
    const bf16* base = qkv + (long)r * QKV_N;

    if (unit < 18) {
        int p = pos[r];
        int col0 = (unit < 16) ? unit * HD_ : (NH_ * HD_ + (unit - 16) * HD_);
        float x1 = __bfloat162float(base[col0 + i]);
        float x2 = __bfloat162float(base[col0 + i + 64]);
        // inv_freq = THETA^(-i/64) = exp(-i * ln(1e6)/64)
        float ang = (float)p * __expf(-(float)i * (13.815510557964274f / 64.0f));
        float sn, cs;
        __sincosf(ang, &sn, &cs);
        float o1 = x1 * cs - x2 * sn;
        float o2 = x2 * cs + x1 * sn;
        if (unit < 16) {
            long ob = (((long)b * NH_ + unit) * S_ + s) * HD_;
            Qr[ob + i] = __float2bfloat16(o1);
            Qr[ob + i + 64] = __float2bfloat16(o2);
        } else {
            int kvh = unit - 16;
            long ob = (((long)b * NKV_ + kvh) * S_ + s) * HD_;
            Kr[ob + i] = __float2bfloat16(o1);
            Kr[ob + i + 64] = __float2bfloat16(o2);
        }
    } else {
        int kvh = unit - 18;
        int col0 = (NH_ + NKV_) * HD_ + kvh * HD_;
        long ob = (((long)b * NKV_ + kvh) * S_ + s) * HD_;
        Vr[ob + i] = base[col0 + i];
        Vr[ob + i + 64] = base[col0 + i + 64];
    }
}

// ---------------------------------------------------------------------------
// flash-style causal attention, 64 q-rows x 64 k-keys tiles, MFMA 16x16x32
__global__ __launch_bounds__(256) void attn_kernel(
    const bf16* __restrict__ Q,   // [B][NH][S][HD]
    const bf16* __restrict__ Kk,  // [B][NKV][S][HD]
    const bf16* __restrict__ V,   // [B][NKV][S][HD]
    bf16* __restrict__ O)         // [B][S][NH*HD]
{
    const int qt = blockIdx.x, h = blockIdx.y, b = blockIdx.z;
    const int kvh = h >> 3;       // rep = NH/NKV = 8
    const int tid = threadIdx.x, wave = tid >> 6, lane = tid & 63;
    const int quad = lane >> 4, l16 = lane & 15;

    __shared__ __align__(16) bf16 Qs[64 * 128];
    __shared__ __align__(16) bf16 Ks[64 * 128];
    __shared__ __align__(16) bf16 Vt[128 * 64];  // transposed: [dim][key]
    __shared__ __align__(16) bf16 Ps[64 * 64];

    const bf16* Qg = Q + (((long)(b * NH_ + h) * S_) + qt * 64) * HD_;
#pragma unroll
    for (int i = 0; i < 4; i++) {
        int cb = i * 256 + wave * 64;
        async_load16(Qg + (size_t)(cb + lane) * 8, Qs + (size_t)cb * 8);
    }

    float m_i[4], l_i[4];
#pragma unroll
    for (int r = 0; r < 4; r++) { m_i[r] = -1e30f; l_i[r] = 0.0f; }
    f32x4 acc_o[8];
#pragma unroll
    for (int i = 0; i < 8; i++) acc_o[i] = {0.f, 0.f, 0.f, 0.f};

    const int vkey = tid & 63, vch = tid >> 6;
    const bf16* Kbase = Kk + ((long)(b * NKV_ + kvh) * S_) * HD_;
    const bf16* Vbase = V + ((long)(b * NKV_ + kvh) * S_) * HD_;

    for (int kt = 0; kt <= qt; kt++) {
        // stage K tile (async) and V tile (register transpose -> Vt)
        const bf16* Kg = Kbase + (long)kt * 64 * HD_;
#pragma unroll
        for (int i = 0; i < 4; i++) {
            int cb = i * 256 + wave * 64;
            async_load16(Kg + (size_t)(cb + lane) * 8, Ks + (size_t)cb * 8);
        }
        const bf16* Vg = Vbase + (long)kt * 64 * HD_;
        bf16x8 vv[4];
#pragma unroll
        for (int j = 0; j < 4; j++)
            vv[j] = *(const bf16x8*)(Vg + vkey * 128 + vch * 32 + j * 8);
#pragma unroll
        for (int j = 0; j < 4; j++) {
            int d0 = vch * 32 + j * 8;
#pragma unroll
            for (int e = 0; e < 8; e++)
                ((short*)Vt)[(d0 + e) * 64 + vkey] = vv[j][e];
        }
        __syncthreads();   // K (vmcnt drained) + Vt visible

        // S = Q K^T for this wave's 16 q-rows
        f32x4 sacc[4];
#pragma unroll
        for (int nt = 0; nt < 4; nt++) sacc[nt] = {0.f, 0.f, 0.f, 0.f};
#pragma unroll
        for (int ks = 0; ks < 4; ks++) {
            bf16x8 a = *(const bf16x8*)(Qs + (wave * 16 + l16) * 128 + ks * 32 + quad * 8);
#pragma unroll
            for (int nt = 0; nt < 4; nt++) {
                bf16x8 bb = *(const bf16x8*)(Ks + (nt * 16 + l16) * 128 + ks * 32 + quad * 8);
                sacc[nt] = __builtin_amdgcn_mfma_f32_16x16x32_bf16(a, bb, sacc[nt], 0, 0, 0);
            }
        }

        // scale + causal mask (C layout: row = quad*4+reg, col = l16)
        const bool diag = (kt == qt);
        float sv[4][4];
#pragma unroll
        for (int nt = 0; nt < 4; nt++) {
            int kcol = nt * 16 + l16;
#pragma unroll
            for (int reg = 0; reg < 4; reg++) {
                int qrow = wave * 16 + quad * 4 + reg;
                float x = sacc[nt][reg] * SCALE_;
                if (diag && kcol > qrow) x = -1e30f;
                sv[nt][reg] = x;
            }
        }
        // online softmax: row stats across 16 lanes of the quad
        float alpha[4];
#pragma unroll
        for (int reg = 0; reg < 4; reg++) {
            float v = fmaxf(fmaxf(sv[0][reg], sv[1][reg]), fmaxf(sv[2][reg], sv[3][reg]));
            v = fmaxf(v, __shfl_xor(v, 1, 16));
            v = fmaxf(v, __shfl_xor(v, 2, 16));
            v = fmaxf(v, __shfl_xor(v, 4, 16));
            v = fmaxf(v, __shfl_xor(v, 8, 16));
            float mn = fmaxf(m_i[reg], v);
            alpha[reg] = __expf(m_i[reg] - mn);
            m_i[reg] = mn;
        }
#pragma unroll
        for (int reg = 0; reg < 4; reg++) {
            float rs = 0.f;
#pragma unroll
            for (int nt = 0; nt < 4; nt++) {
                float p = __expf(sv[nt][reg] - m_i[reg]);
                rs += p;
                Ps[(wave * 16 + quad * 4 + reg) * 64 + nt * 16 + l16] = __float2bfloat16(p);
            }
            rs += __shfl_xor(rs, 1, 16);
            rs += __shfl_xor(rs, 2, 16);
            rs += __shfl_xor(rs, 4, 16);
            rs += __shfl_xor(rs, 8, 16);
            l_i[reg] = l_i[reg] * alpha[reg] + rs;
        }
        // rescale O
#pragma unroll
        for (int n8 = 0; n8 < 8; n8++)
#pragma unroll
            for (int reg = 0; reg < 4; reg++) acc_o[n8][reg] *= alpha[reg];

        __syncthreads();   // Ps visible (conservative: also pins ds_write->ds_read order)

        // O += P V  (A = Ps rows of this wave, B = Vt)
#pragma unroll
        for (int ks2 = 0; ks2 < 2; ks2++) {
            bf16x8 a = *(const bf16x8*)(Ps + (wave * 16 + l16) * 64 + ks2 * 32 + quad * 8);
#pragma unroll
            for (int n8 = 0; n8 < 8; n8++) {
                bf16x8 bb = *(const bf16x8*)(Vt + (n8 * 16 + l16) * 64 + ks2 * 32 + quad * 8);
                acc_o[n8] = __builtin_amdgcn_mfma_f32_16x16x32_bf16(a, bb, acc_o[n8], 0, 0, 0);
            }
        }
        __syncthreads();   // before next iter's staging overwrites Ks/Vt
    }

    // epilogue: O /= l, write [B][S][NH*HD]
#pragma unroll
    for (int n8 = 0; n8 < 8; n8++) {
#pragma unroll
        for (int reg = 0; reg < 4; reg++) {
            int qrow = qt * 64 + wave * 16 + quad * 4 + reg;
            float v = acc_o[n8][reg] / l_i[reg];
            O[((long)b * S_ + qrow) * (NH_ * HD_) + h * HD_ + n8 * 16 + l16] =
                __float2bfloat16(v);
        }
    }
}

// ---------------------------------------------------------------------------
extern "C" void kernel_launch(void* const* d_in, const int* in_sizes, int n_in,
                              void* d_out, int out_size, void* d_ws, size_t ws_size,
                              hipStream_t stream) {
    const int*   pos  = (const int*)d_in[0];
    const float* X    = (const float*)d_in[1];
    const float* Wqkv = (const float*)d_in[2];
    const float* bqkv = (const float*)d_in[3];
    const float* Wo   = (const float*)d_in[4];
    float* out = (float*)d_out;

    char* ws = (char*)d_ws;
    bf16* Xb    = (bf16*)ws;  ws += (size_t)B_ * S_ * HID_ * 2;           // 16.8 MB
    bf16* Wqkvt = (bf16*)ws;  ws += (size_t)QKV_N * HID_ * 2;             // 10.5 MB
    bf16* Wot   = (bf16*)ws;  ws += (size_t)HID_ * HID_ * 2;              // 8.4 MB
    bf16* qkvb  = (bf16*)ws;  ws += (size_t)B_ * S_ * QKV_N * 2;          // 21 MB
    bf16* Qr    = (bf16*)ws;  ws += (size_t)B_ * NH_ * S_ * HD_ * 2;      // 16.8 MB
    bf16* Kr    = (bf16*)ws;  ws += (size_t)B_ * NKV_ * S_ * HD_ * 2;     // 2.1 MB
    bf16* Vr    = (bf16*)ws;  ws += (size_t)B_ * NKV_ * S_ * HD_ * 2;     // 2.1 MB
    bf16* AO    = (bf16*)ws;  ws += (size_t)B_ * S_ * NH_ * HD_ * 2;      // 16.8 MB

    // 1. casts / transposes
    cast_f32_bf16<<<(B_ * S_ * HID_) / (256 * 4), 256, 0, stream>>>(X, Xb);
    transpose_cast<<<dim3(QKV_N / 32, HID_ / 32), 256, 0, stream>>>(Wqkv, Wqkvt, HID_, QKV_N);
    transpose_cast<<<dim3(HID_ / 32, HID_ / 32), 256, 0, stream>>>(Wo, Wot, HID_, HID_);

    // 2. QKV projection + bias (bf16 out)
    gemm128<true, true><<<dim3(QKV_N / 128, (B_ * S_) / 128), 256, 0, stream>>>(
        Xb, Wqkvt, bqkv, qkvb, B_ * S_, QKV_N, HID_);

    // 3. RoPE + split
    rope_split<<<(B_ * S_ * 20 * 64) / 256, 256, 0, stream>>>(qkvb, pos, Qr, Kr, Vr);

    // 4. causal GQA attention
    attn_kernel<<<dim3(S_ / 64, NH_, B_), 256, 0, stream>>>(Qr, Kr, Vr, AO);

    // 5. output projection (fp32 out)
    gemm128<false, false><<<dim3(HID_ / 128, (B_ * S_) / 128), 256, 0, stream>>>(
        AO, Wot, nullptr, out, B_ * S_, HID_, HID_);
}

// Round 2
// 341.531 us; speedup vs baseline: 1.7021x; 1.7021x over previous
//
#include <hip/hip_runtime.h>
#include <hip/hip_bf16.h>
#include <stdint.h>

typedef __hip_bfloat16 bf16;
typedef __attribute__((ext_vector_type(4))) float f32x4;
typedef __attribute__((ext_vector_type(8))) short bf16x8;

#define B_  2
#define S_  2048
#define HID_ 2048
#define NH_ 16
#define NKV_ 2
#define HD_ 128
#define QKV_N 2560           // (NH + 2*NKV) * HD
#define SCALE_ 0.08838834764831845f

// ---------------------------------------------------------------------------
// async 16B global->LDS (wave-uniform LDS base + lane*16)
__device__ __forceinline__ void async_load16(const void* g, void* l) {
    __builtin_amdgcn_global_load_lds(
        (const __attribute__((address_space(1))) unsigned int*)(uintptr_t)g,
        (__attribute__((address_space(3))) unsigned int*)(uintptr_t)l,
        16, 0, 0);
}

// ---------------------------------------------------------------------------
// cast fp32 -> bf16, 4 elems/thread, exact grid
__global__ void cast_f32_bf16(const float* __restrict__ in, bf16* __restrict__ out) {
    long idx = ((long)blockIdx.x * 256 + threadIdx.x) * 4;
    float4 v = *(const float4*)(in + idx);
    bf16 o[4];
    o[0] = __float2bfloat16(v.x); o[1] = __float2bfloat16(v.y);
    o[2] = __float2bfloat16(v.z); o[3] = __float2bfloat16(v.w);
    *(ulong1*)(out + idx) = *(ulong1*)o;
}

// transpose + cast: in fp32 [R][C] -> out bf16 [C][R]
__global__ void transpose_cast(const float* __restrict__ in, bf16* __restrict__ out,
                               int R, int C) {
    __shared__ float t[32][33];
    int tx = threadIdx.x & 31, ty = threadIdx.x >> 5;   // 32x8
    int c = blockIdx.x * 32 + tx;
#pragma unroll
    for (int j = 0; j < 4; j++) {
        int r = blockIdx.y * 32 + ty + j * 8;
        t[ty + j * 8][tx] = in[(long)r * C + c];
    }
    __syncthreads();
#pragma unroll
    for (int j = 0; j < 4; j++) {
        int cc = blockIdx.x * 32 + ty + j * 8;
        int rr = blockIdx.y * 32 + tx;
        out[(long)cc * R + rr] = __float2bfloat16(t[tx][ty + j * 8]);
    }
}

// bf16 transpose of the V slab: qkv[b][s][2304 + j] -> VtG[b][j][s], j in 0..255
__global__ void v_transpose(const bf16* __restrict__ qkv, bf16* __restrict__ VtG) {
    __shared__ bf16 t[32][33];
    int tx = threadIdx.x & 31, ty = threadIdx.x >> 5;   // 32x8
    int b = blockIdx.z;
    int j0 = blockIdx.x * 32;
    int s0 = blockIdx.y * 32;
#pragma unroll
    for (int jj = 0; jj < 4; jj++) {
        int s = s0 + ty + jj * 8;
        t[ty + jj * 8][tx] =
            qkv[((long)b * S_ + s) * QKV_N + (NH_ + NKV_) * HD_ + j0 + tx];
    }
    __syncthreads();
#pragma unroll
    for (int jj = 0; jj < 4; jj++) {
        int j = j0 + ty + jj * 8;
        VtG[((long)b * (2 * HD_) + j) * S_ + s0 + tx] = t[tx][ty + jj * 8];
    }
}

// ---------------------------------------------------------------------------
// m97-style GEMM: C[M,N] = A[M,K] * Bt[N,K]^T (+bias), 128x128 tile, BK=32
// LDS chunks XOR-swizzled (slot c holds global chunk c ^ (row&3)) -> 4-way max
template <bool HAS_BIAS, bool OUT_BF16>
__global__ __launch_bounds__(256) void gemm128(
    const bf16* __restrict__ A, const bf16* __restrict__ Bt,
    const float* __restrict__ bias, void* __restrict__ Cout,
    int M, int N, int K)
{
    __shared__ __align__(16) bf16 As[128 * 32];
    __shared__ __align__(16) bf16 Bs[128 * 32];
    const int tid = threadIdx.x;
    const int wave = tid >> 6, lane = tid & 63;
    const int quad = lane >> 4, l16 = lane & 15;
    const int wr = wave >> 1, wc = wave & 1;
    const long row0 = (long)blockIdx.y * 128;
    const long col0 = (long)blockIdx.x * 128;

    f32x4 acc[4][4];
#pragma unroll
    for (int i = 0; i < 4; i++)
#pragma unroll
        for (int j = 0; j < 4; j++) acc[i][j] = {0.f, 0.f, 0.f, 0.f};

    for (int k0 = 0; k0 < K; k0 += 32) {
        __syncthreads();
#pragma unroll
        for (int i = 0; i < 2; i++) {
            int cb = i * 256 + wave * 64;           // wave-uniform chunk base
            int c = cb + lane;
            int r = c >> 2, kc = c & 3;
            int gc = kc ^ (r & 3);                  // swizzled global chunk
            async_load16(A + (row0 + r) * K + k0 + gc * 8, As + (size_t)cb * 8);
            async_load16(Bt + (col0 + r) * K + k0 + gc * 8, Bs + (size_t)cb * 8);
        }
        __syncthreads();   // drains vmcnt before ds_read

        bf16x8 af[4], bfr[4];
        const int slot = (quad ^ (l16 & 3)) * 8;
#pragma unroll
        for (int mi = 0; mi < 4; mi++)
            af[mi] = *(const bf16x8*)(As + (wr * 64 + mi * 16 + l16) * 32 + slot);
#pragma unroll
        for (int ni = 0; ni < 4; ni++)
            bfr[ni] = *(const bf16x8*)(Bs + (wc * 64 + ni * 16 + l16) * 32 + slot);
#pragma unroll
        for (int mi = 0; mi < 4; mi++)
#pragma unroll
            for (int ni = 0; ni < 4; ni++)
                acc[mi][ni] = __builtin_amdgcn_mfma_f32_16x16x32_bf16(
                    af[mi], bfr[ni], acc[mi][ni], 0, 0, 0);
    }

#pragma unroll
    for (int mi = 0; mi < 4; mi++) {
        long r = row0 + wr * 64 + mi * 16 + quad * 4;
#pragma unroll
        for (int ni = 0; ni < 4; ni++) {
            long c = col0 + wc * 64 + ni * 16 + l16;
            float bv = HAS_BIAS ? bias[c] : 0.0f;
#pragma unroll
            for (int reg = 0; reg < 4; reg++) {
                float v = acc[mi][ni][reg] + bv;
                if (OUT_BF16)
                    ((bf16*)Cout)[(r + reg) * N + c] = __float2bfloat16(v);
                else
                    ((float*)Cout)[(r + reg) * N + c] = v;
            }
        }
    }
}

// ---------------------------------------------------------------------------
// RoPE + split qkv -> Q [B,NH,S,HD], K [B,NKV,S,HD]  (V handled by v_transpose)
__global__ void rope_split(const bf16* __restrict__ qkv, const int* __restrict__ pos,
                           bf16* __restrict__ Qr, bf16* __restrict__ Kr)
{
    int idx = blockIdx.x * 256 + threadIdx.x;    // B*S*18*64 total
    int r = idx / 1152;                          // b*S + s
    int rem = idx - r * 1152;
    int unit = rem >> 6;                         // 0..17
    int i = rem & 63;
    int b = r >> 11;                             // S=2048
    int s = r & 2047;
    const bf16* base = qkv + (long)r * QKV_N;

    int p = pos[r];
    int col0 = (unit < 16) ? unit * HD_ : (NH_ * HD_ + (unit - 16) * HD_);
    float x1 = __bfloat162float(base[col0 + i]);
    float x2 = __bfloat162float(base[col0 + i + 64]);
    float ang = (float)p * __expf(-(float)i * (13.815510557964274f / 64.0f));
    float sn, cs;
    __sincosf(ang, &sn, &cs);
    float o1 = x1 * cs - x2 * sn;
    float o2 = x2 * cs + x1 * sn;
    if (unit < 16) {
        long ob = (((long)b * NH_ + unit) * S_ + s) * HD_;
        Qr[ob + i] = __float2bfloat16(o1);
        Qr[ob + i + 64] = __float2bfloat16(o2);
    } else {
        int kvh = unit - 16;
        long ob = (((long)b * NKV_ + kvh) * S_ + s) * HD_;
        Kr[ob + i] = __float2bfloat16(o1);
        Kr[ob + i + 64] = __float2bfloat16(o2);
    }
}

// ---------------------------------------------------------------------------
// flash-style causal attention, 64-row q-tiles (paired for balance), 64-key
// tiles, swizzled LDS (<=2-way conflicts), Q frags in registers, V staged
// pre-transposed.  LDS = 48 KB -> 3 blocks/CU.
__global__ __launch_bounds__(256) void attn_kernel(
    const bf16* __restrict__ Q,   // [B][NH][S][HD]
    const bf16* __restrict__ Kk,  // [B][NKV][S][HD]
    const bf16* __restrict__ Vt,  // [B][NKV*HD][S]  (transposed V)
    bf16* __restrict__ O)         // [B][S][NH*HD]
{
    const int pair = blockIdx.x, h = blockIdx.y, b = blockIdx.z;
    const int kvh = h >> 3;       // rep = NH/NKV = 8
    const int tid = threadIdx.x, wave = tid >> 6, lane = tid & 63;
    const int quad = lane >> 4, l16 = lane & 15;
    const int NT = S_ / 64;       // 32 k-tiles

    __shared__ __align__(16) bf16 Ks[64 * 128];   // [key][16 chunks, swz key&15]
    __shared__ __align__(16) bf16 Vts[128 * 64];  // [dim][8 chunks, swz dim&7]
    __shared__ __align__(16) bf16 QPs[64 * 128];  // Q staging; [64][64] Ps alias

    const bf16* Kbase = Kk + ((long)(b * NKV_ + kvh) * S_) * HD_;
    const bf16* Vbase = Vt + ((long)b * (2 * HD_) + kvh * HD_) * (long)S_;

#pragma unroll 1
    for (int sub = 0; sub < 2; sub++) {
        const int qt = sub ? (NT - 1 - pair) : pair;

        // stage Q tile (swizzled) and hoist this wave's A-fragments to regs
        const bf16* Qg = Q + (((long)(b * NH_ + h) * S_) + qt * 64) * HD_;
#pragma unroll
        for (int i = 0; i < 4; i++) {
            int cb = i * 256 + wave * 64;
            int c = cb + lane, r = c >> 4, sc = c & 15;
            async_load16(Qg + r * HD_ + (sc ^ (r & 15)) * 8, QPs + (size_t)cb * 8);
        }
        __syncthreads();
        bf16x8 qa[4];
#pragma unroll
        for (int ks = 0; ks < 4; ks++)
            qa[ks] = *(const bf16x8*)(QPs + (wave * 16 + l16) * 128 +
                                      (((ks * 4 + quad) ^ l16) * 8));
        __syncthreads();   // QPs now reusable as Ps

        float m_i[4], l_i[4];
#pragma unroll
        for (int r = 0; r < 4; r++) { m_i[r] = -1e30f; l_i[r] = 0.0f; }
        f32x4 acc_o[8];
#pragma unroll
        for (int i = 0; i < 8; i++) acc_o[i] = {0.f, 0.f, 0.f, 0.f};

        for (int kt = 0; kt <= qt; kt++) {
            // stage K tile + Vt tile (both swizzled)
            const bf16* Kg = Kbase + (long)kt * 64 * HD_;
#pragma unroll
            for (int i = 0; i < 4; i++) {
                int cb = i * 256 + wave * 64;
                int c = cb + lane, r = c >> 4, sc = c & 15;
                async_load16(Kg + r * HD_ + (sc ^ (r & 15)) * 8, Ks + (size_t)cb * 8);
            }
            const bf16* Vg = Vbase + kt * 64;
#pragma unroll
            for (int i = 0; i < 4; i++) {
                int cb = i * 256 + wave * 64;
                int c = cb + lane, r = c >> 3, sc = c & 7;
                async_load16(Vg + (long)r * S_ + (sc ^ (r & 7)) * 8,
                             Vts + (size_t)cb * 8);
            }
            __syncthreads();

            // S = Q K^T for this wave's 16 q-rows
            f32x4 sacc[4];
#pragma unroll
            for (int nt = 0; nt < 4; nt++) sacc[nt] = {0.f, 0.f, 0.f, 0.f};
#pragma unroll
            for (int ks = 0; ks < 4; ks++) {
#pragma unroll
                for (int nt = 0; nt < 4; nt++) {
                    bf16x8 bb = *(const bf16x8*)(Ks + (nt * 16 + l16) * 128 +
                                                 (((ks * 4 + quad) ^ l16) * 8));
                    sacc[nt] = __builtin_amdgcn_mfma_f32_16x16x32_bf16(
                        qa[ks], bb, sacc[nt], 0, 0, 0);
                }
            }

            // scale + causal mask (C layout: row = quad*4+reg, col = l16)
            const bool diag = (kt == qt);
            float sv[4][4];
#pragma unroll
            for (int nt = 0; nt < 4; nt++) {
                int kcol = nt * 16 + l16;
#pragma unroll
                for (int reg = 0; reg < 4; reg++) {
                    int qrow = wave * 16 + quad * 4 + reg;
                    float x = sacc[nt][reg] * SCALE_;
                    if (diag && kcol > qrow) x = -1e30f;
                    sv[nt][reg] = x;
                }
            }
            // online softmax: row stats across 16 lanes of the quad
            float alpha[4];
#pragma unroll
            for (int reg = 0; reg < 4; reg++) {
                float v = fmaxf(fmaxf(sv[0][reg], sv[1][reg]),
                                fmaxf(sv[2][reg], sv[3][reg]));
                v = fmaxf(v, __shfl_xor(v, 1, 16));
                v = fmaxf(v, __shfl_xor(v, 2, 16));
                v = fmaxf(v, __shfl_xor(v, 4, 16));
                v = fmaxf(v, __shfl_xor(v, 8, 16));
                float mn = fmaxf(m_i[reg], v);
                alpha[reg] = __expf(m_i[reg] - mn);
                m_i[reg] = mn;
            }
#pragma unroll
            for (int reg = 0; reg < 4; reg++) {
                int prow = wave * 16 + quad * 4 + reg;
                float rs = 0.f;
#pragma unroll
                for (int nt = 0; nt < 4; nt++) {
                    float p = __expf(sv[nt][reg] - m_i[reg]);
                    rs += p;
                    int slot = (nt * 2 + (l16 >> 3)) ^ (prow & 7);
                    QPs[prow * 64 + slot * 8 + (l16 & 7)] = __float2bfloat16(p);
                }
                rs += __shfl_xor(rs, 1, 16);
                rs += __shfl_xor(rs, 2, 16);
                rs += __shfl_xor(rs, 4, 16);
                rs += __shfl_xor(rs, 8, 16);
                l_i[reg] = l_i[reg] * alpha[reg] + rs;
            }
            // rescale O
#pragma unroll
            for (int n8 = 0; n8 < 8; n8++)
#pragma unroll
                for (int reg = 0; reg < 4; reg++) acc_o[n8][reg] *= alpha[reg];

            __syncthreads();   // Ps visible

            // O += P V  (A = Ps rows of this wave, B = Vts)
#pragma unroll
            for (int ks2 = 0; ks2 < 2; ks2++) {
                int pslot = ((ks2 * 4 + quad) ^ (l16 & 7)) * 8;
                bf16x8 a = *(const bf16x8*)(QPs + (wave * 16 + l16) * 64 + pslot);
#pragma unroll
                for (int n8 = 0; n8 < 8; n8++) {
                    bf16x8 bb = *(const bf16x8*)(Vts + (n8 * 16 + l16) * 64 + pslot);
                    acc_o[n8] = __builtin_amdgcn_mfma_f32_16x16x32_bf16(
                        a, bb, acc_o[n8], 0, 0, 0);
                }
            }
            __syncthreads();   // before next iter's staging overwrites Ks/Vts/Ps
        }

        // epilogue: O /= l, write [B][S][NH*HD]
#pragma unroll
        for (int n8 = 0; n8 < 8; n8++) {
#pragma unroll
            for (int reg = 0; reg < 4; reg++) {
                int qrow = qt * 64 + wave * 16 + quad * 4 + reg;
                float v = acc_o[n8][reg] / l_i[reg];
                O[((long)b * S_ + qrow) * (NH_ * HD_) + h * HD_ + n8 * 16 + l16] =
                    __float2bfloat16(v);
            }
        }
    }
}

// ---------------------------------------------------------------------------
extern "C" void kernel_launch(void* const* d_in, const int* in_sizes, int n_in,
                              void* d_out, int out_size, void* d_ws, size_t ws_size,
                              hipStream_t stream) {
    const int*   pos  = (const int*)d_in[0];
    const float* X    = (const float*)d_in[1];
    const float* Wqkv = (const float*)d_in[2];
    const float* bqkv = (const float*)d_in[3];
    const float* Wo   = (const float*)d_in[4];
    float* out = (float*)d_out;

    char* ws = (char*)d_ws;
    bf16* Xb    = (bf16*)ws;  ws += (size_t)B_ * S_ * HID_ * 2;           // 16.8 MB
    bf16* Wqkvt = (bf16*)ws;  ws += (size_t)QKV_N * HID_ * 2;             // 10.5 MB
    bf16* Wot   = (bf16*)ws;  ws += (size_t)HID_ * HID_ * 2;              // 8.4 MB
    bf16* qkvb  = (bf16*)ws;  ws += (size_t)B_ * S_ * QKV_N * 2;          // 21 MB
    bf16* Qr    = (bf16*)ws;  ws += (size_t)B_ * NH_ * S_ * HD_ * 2;      // 16.8 MB
    bf16* Kr    = (bf16*)ws;  ws += (size_t)B_ * NKV_ * S_ * HD_ * 2;     // 2.1 MB
    bf16* VtG   = (bf16*)ws;  ws += (size_t)B_ * NKV_ * HD_ * S_ * 2;     // 2.1 MB
    bf16* AO    = (bf16*)ws;  ws += (size_t)B_ * S_ * NH_ * HD_ * 2;      // 16.8 MB

    // 1. casts / transposes
    cast_f32_bf16<<<(B_ * S_ * HID_) / (256 * 4), 256, 0, stream>>>(X, Xb);
    transpose_cast<<<dim3(QKV_N / 32, HID_ / 32), 256, 0, stream>>>(Wqkv, Wqkvt, HID_, QKV_N);
    transpose_cast<<<dim3(HID_ / 32, HID_ / 32), 256, 0, stream>>>(Wo, Wot, HID_, HID_);

    // 2. QKV projection + bias (bf16 out)
    gemm128<true, true><<<dim3(QKV_N / 128, (B_ * S_) / 128), 256, 0, stream>>>(
        Xb, Wqkvt, bqkv, qkvb, B_ * S_, QKV_N, HID_);

    // 3. RoPE + split (Q,K) and V transpose
    rope_split<<<(B_ * S_ * 18 * 64) / 256, 256, 0, stream>>>(qkvb, pos, Qr, Kr);
    v_transpose<<<dim3((2 * HD_) / 32, S_ / 32, B_), 256, 0, stream>>>(qkvb, VtG);

    // 4. causal GQA attention (paired q-tiles for load balance)
    attn_kernel<<<dim3(S_ / 128, NH_, B_), 256, 0, stream>>>(Qr, Kr, VtG, AO);

    // 5. output projection (fp32 out)
    gemm128<false, false><<<dim3(HID_ / 128, (B_ * S_) / 128), 256, 0, stream>>>(
        AO, Wot, nullptr, out, B_ * S_, HID_, HID_);
}